// Round 3
// baseline (6225.804 us; speedup 1.0000x reference)
//
#include <hip/hip_runtime.h>
#include <hip/hip_fp16.h>
#include <stdint.h>

// Gated LSTM: B=64, T=2048, I=128, H=256, O=1.
// R3 structure: 16 persistent WGs = 4 batch-groups (16 batches, M=16 full)
//             x 4 N-slices (p: 256 z-rows = 64 h-outputs each).
// W slice ([W_ih;W_hh] K=384 x 256 rows) = 192 KB f16 resident in regs
// (48 h8_t frags/thread; R2 showed compiler uses AGPRs -> ~330/512 regs).
// Per step: issue partner polls -> stage gated-x -> x-part MFMAs (K 0..127)
// overlap the poll latency -> stage partner h -> h-part MFMAs -> epilogue.
// Exchange: tag-embedded {t+1 : 2xf16} 64-bit relaxed agent atomics, double
// buffered by t&1 (monotone tags; 0xAA ws poison never aliases a tag).

#define NT 2048
#define NI 128
#define NH 256
#define NG 4      // batch groups
#define NP 4      // N-slice WGs per group
#define BG 16     // batches per group
#define JS 64     // h-outputs per WG
#define HBUF 8192 // uint64 words per exchange buffer

typedef _Float16 h8_t __attribute__((ext_vector_type(8)));
typedef _Float16 h4_t __attribute__((ext_vector_type(4)));
typedef float f4_t __attribute__((ext_vector_type(4)));

__device__ __forceinline__ float sigm(float x) {
  return __builtin_amdgcn_rcpf(1.f + __expf(-x));
}
__device__ __forceinline__ float tanh_f(float x) {
  return 1.f - 2.f * __builtin_amdgcn_rcpf(1.f + __expf(2.f * x));
}
__device__ __forceinline__ uint32_t f16b(float x) {
  _Float16 h = (_Float16)x;
  return (uint32_t)__builtin_bit_cast(uint16_t, h);
}
__device__ __forceinline__ _Float16 b2h(uint32_t u) {
  return __builtin_bit_cast(_Float16, (uint16_t)(u & 0xffffu));
}

// ex (uint64): [buf2][HBUF]: slot = (((g*4+p)*16+b)*16+jl2)*2 + w
//              partials at 2*HBUF: (g*4+p)*16 + b

__launch_bounds__(256, 1)
__global__ void lstm_persist(
    const float* __restrict__ xd, const float* __restrict__ w,
    const float* __restrict__ W_ih, const float* __restrict__ b_ih,
    const float* __restrict__ W_hh, const float* __restrict__ b_hh,
    const float* __restrict__ W_out, const float* __restrict__ b_out,
    float* __restrict__ out, uint64_t* ex)
{
  const int bid = blockIdx.x;
  const int g = bid >> 2;       // batch group
  const int p = bid & 3;        // N-slice
  const int tid = threadIdx.x;
  const int lane = tid & 63;
  const int wv = tid >> 6;      // wave 0..3
  const int q  = lane >> 4;     // 0..3
  const int cc = lane & 15;
  const int b   = tid >> 4;     // epilogue batch 0..15
  const int jl2 = tid & 15;     // epilogue j-quad index 0..15

  // A-tile: [m=batch 16][k: 0..127 gated x, 128..383 h], row pad 392
  __shared__ _Float16 Alds[16][392];
  // Z transposed: [m 16][local z-row 256], pad 260 -> b128 epilogue reads
  __shared__ float Zlds[16][260];

  for (int i = tid; i < 16 * 392; i += 256) (&Alds[0][0])[i] = (_Float16)0.f;

  // ---- W B-fragments (48/thread), resident in registers/AGPRs ----
  // wave wv owns n-tiles nt_g = wv*4 + ntl; local z-row r = 16*nt_g + cc;
  // jl = r>>2, gate = r&3; global row R = gate*256 + p*64 + jl.
  h8_t wf[4][12];
  for (int ntl = 0; ntl < 4; ++ntl) {
    int r = 16 * (wv * 4 + ntl) + cc;
    int R = (r & 3) * NH + p * JS + (r >> 2);
    for (int kt = 0; kt < 12; ++kt) {
      int k = kt * 32 + q * 8;
      const float* s = (k < NI) ? (W_ih + (size_t)R * NI + k)
                                : (W_hh + (size_t)R * NH + (k - NI));
      f4_t lo = *(const f4_t*)s;
      f4_t hi = *(const f4_t*)(s + 4);
      h8_t hh;
      hh[0] = (_Float16)lo[0]; hh[1] = (_Float16)lo[1];
      hh[2] = (_Float16)lo[2]; hh[3] = (_Float16)lo[3];
      hh[4] = (_Float16)hi[0]; hh[5] = (_Float16)hi[1];
      hh[6] = (_Float16)hi[2]; hh[7] = (_Float16)hi[3];
      wf[ntl][kt] = hh;
    }
  }

  // ---- biases for epilogue pairs (b, j = p*64 + jl2*4 + i) ----
  float bias[4][4];
  #pragma unroll
  for (int i = 0; i < 4; ++i) {
    int jg = p * JS + jl2 * 4 + i;
    #pragma unroll
    for (int gate = 0; gate < 4; ++gate)
      bias[i][gate] = b_ih[gate * NH + jg] + b_hh[gate * NH + jg];
  }

  // partner slots
  int pp[3]; { int c = 0; for (int i = 0; i < 4; ++i) if (i != p) pp[c++] = i; }
  int psl[3];
  #pragma unroll
  for (int s = 0; s < 3; ++s)
    psl[s] = (((g * 4 + pp[s]) * 16 + b) * 16 + jl2) * 2;
  const int myslot = (((g * 4 + p) * 16 + b) * 16 + jl2) * 2;

  float cst[4] = {0.f, 0.f, 0.f, 0.f};
  float hval[4] = {0.f, 0.f, 0.f, 0.f};

  // x prefetch (one step ahead)
  const size_t xrow = ((size_t)(g * BG + b) * NT) * NI + jl2 * 8;
  f4_t xa = *(const f4_t*)(xd + xrow);
  f4_t xb = *(const f4_t*)(xd + xrow + 4);
  f4_t wa = *(const f4_t*)(w + xrow);
  f4_t wb = *(const f4_t*)(w + xrow + 4);

  __syncthreads();   // Alds zeros staged

  for (int t = 0; t < NT; ++t) {
    // ---- issue partner polls (checked after x-MFMAs) ----
    uint64_t pv[6];
    const uint64_t* hb = ex + (t & 1) * HBUF;
    if (t > 0) {
      #pragma unroll
      for (int s = 0; s < 3; ++s) {
        pv[2 * s]     = __hip_atomic_load(hb + psl[s], __ATOMIC_RELAXED,
                                          __HIP_MEMORY_SCOPE_AGENT);
        pv[2 * s + 1] = __hip_atomic_load(hb + psl[s] + 1, __ATOMIC_RELAXED,
                                          __HIP_MEMORY_SCOPE_AGENT);
      }
    }

    // ---- stage gated x_t (from prefetched regs), prefetch t+1 ----
    h8_t gx;
    gx[0] = (_Float16)(xa[0] * sigm(wa[0]));
    gx[1] = (_Float16)(xa[1] * sigm(wa[1]));
    gx[2] = (_Float16)(xa[2] * sigm(wa[2]));
    gx[3] = (_Float16)(xa[3] * sigm(wa[3]));
    gx[4] = (_Float16)(xb[0] * sigm(wb[0]));
    gx[5] = (_Float16)(xb[1] * sigm(wb[1]));
    gx[6] = (_Float16)(xb[2] * sigm(wb[2]));
    gx[7] = (_Float16)(xb[3] * sigm(wb[3]));
    *(h8_t*)(&Alds[b][jl2 * 8]) = gx;
    {
      size_t xo = xrow + (size_t)((t + 1 < NT) ? t + 1 : NT - 1) * NI;
      xa = *(const f4_t*)(xd + xo);
      xb = *(const f4_t*)(xd + xo + 4);
      wa = *(const f4_t*)(w + xo);
      wb = *(const f4_t*)(w + xo + 4);
    }
    __syncthreads();                     // barrier A: x region staged

    // ---- x-part MFMAs (K 0..127) while polls are in flight ----
    f4_t acc[4];
    #pragma unroll
    for (int n = 0; n < 4; ++n) acc[n] = (f4_t){0.f, 0.f, 0.f, 0.f};
    #pragma unroll
    for (int kt = 0; kt < 4; ++kt) {
      h8_t af = *(const h8_t*)(&Alds[cc][kt * 32 + q * 8]);
      #pragma unroll
      for (int n = 0; n < 4; ++n)
        acc[n] = __builtin_amdgcn_mfma_f32_16x16x32_f16(af, wf[n][kt], acc[n], 0, 0, 0);
    }

    // ---- check polls, stage partner h ----
    if (t > 0) {
      unsigned need = 0x7;
      while (need) {
        #pragma unroll
        for (int s = 0; s < 3; ++s) {
          if (!(need & (1u << s))) continue;
          unsigned t0 = (unsigned)(pv[2 * s] >> 32);
          unsigned t1 = (unsigned)(pv[2 * s + 1] >> 32);
          if (t0 == (unsigned)t && t1 == (unsigned)t) {
            uint32_t a0 = (uint32_t)pv[2 * s];
            uint32_t a1 = (uint32_t)pv[2 * s + 1];
            h4_t hp;
            hp[0] = b2h(a0); hp[1] = b2h(a0 >> 16);
            hp[2] = b2h(a1); hp[3] = b2h(a1 >> 16);
            *(h4_t*)(&Alds[b][NI + pp[s] * JS + jl2 * 4]) = hp;
            need &= ~(1u << s);
          } else {
            pv[2 * s]     = __hip_atomic_load(hb + psl[s], __ATOMIC_RELAXED,
                                              __HIP_MEMORY_SCOPE_AGENT);
            pv[2 * s + 1] = __hip_atomic_load(hb + psl[s] + 1, __ATOMIC_RELAXED,
                                              __HIP_MEMORY_SCOPE_AGENT);
          }
        }
      }
    }
    __syncthreads();                     // barrier B: h region staged

    // ---- h-part MFMAs (K 128..383) ----
    #pragma unroll
    for (int kt = 4; kt < 12; ++kt) {
      h8_t af = *(const h8_t*)(&Alds[cc][kt * 32 + q * 8]);
      #pragma unroll
      for (int n = 0; n < 4; ++n)
        acc[n] = __builtin_amdgcn_mfma_f32_16x16x32_f16(af, wf[n][kt], acc[n], 0, 0, 0);
    }
    // C layout: col n = cc (local z-row 16*nt_g+cc), row m = q*4+rr
    #pragma unroll
    for (int n = 0; n < 4; ++n) {
      int zr = 16 * (wv * 4 + n) + cc;
      #pragma unroll
      for (int rr = 0; rr < 4; ++rr)
        Zlds[q * 4 + rr][zr] = acc[n][rr];
    }
    __syncthreads();                     // barrier C: Z staged

    // ---- epilogue: 4 (b,j) pairs per thread ----
    h4_t hh;
    #pragma unroll
    for (int i = 0; i < 4; ++i) {
      f4_t zz = *(const f4_t*)(&Zlds[b][(jl2 * 4 + i) * 4]);
      float zi = zz[0] + bias[i][0];
      float zf = zz[1] + bias[i][1];
      float zg = zz[2] + bias[i][2];
      float zo = zz[3] + bias[i][3];
      cst[i] = sigm(zf) * cst[i] + sigm(zi) * tanh_f(zg);
      hval[i] = sigm(zo) * tanh_f(cst[i]);
      hh[i] = (_Float16)hval[i];
    }
    *(h4_t*)(&Alds[b][NI + p * JS + jl2 * 4]) = hh;   // own slice for t+1
    uint64_t tagw = ((uint64_t)(unsigned)(t + 1)) << 32;
    uint64_t w0 = tagw | (f16b(hval[0]) | (f16b(hval[1]) << 16));
    uint64_t w1 = tagw | (f16b(hval[2]) | (f16b(hval[3]) << 16));
    uint64_t* ob = ex + ((t + 1) & 1) * HBUF + myslot;
    __hip_atomic_store(ob, w0, __ATOMIC_RELAXED, __HIP_MEMORY_SCOPE_AGENT);
    __hip_atomic_store(ob + 1, w1, __ATOMIC_RELAXED, __HIP_MEMORY_SCOPE_AGENT);
    // next step's barrier A orders epilogue LDS writes vs MFMA reads
  }

  // ---- output: out[b] = h_T . W_out + b_out ----
  // per-WG partial over its 64 j, reduced across jl2 lanes, then across p.
  f4_t wo = *(const f4_t*)(W_out + p * JS + jl2 * 4);
  float ps = hval[0] * wo[0] + hval[1] * wo[1] + hval[2] * wo[2] + hval[3] * wo[3];
  #pragma unroll
  for (int m = 1; m < 16; m <<= 1) ps += __shfl_xor(ps, m, 64);
  uint64_t* ex2 = ex + 2 * HBUF;
  if (jl2 == 0) {
    uint64_t pw = (((uint64_t)2049u) << 32) | (uint64_t)__float_as_uint(ps);
    __hip_atomic_store(ex2 + (g * 4 + p) * 16 + b, pw,
                       __ATOMIC_RELAXED, __HIP_MEMORY_SCOPE_AGENT);
  }
  if (p == 0 && tid < 16) {
    float sum = b_out[0];
    unsigned need = 0xF;
    while (need) {
      #pragma unroll
      for (int pq = 0; pq < 4; ++pq) {
        if (!(need & (1u << pq))) continue;
        uint64_t v = __hip_atomic_load(ex2 + (g * 4 + pq) * 16 + tid,
                                       __ATOMIC_RELAXED, __HIP_MEMORY_SCOPE_AGENT);
        if ((unsigned)(v >> 32) == 2049u) {
          sum += __uint_as_float((unsigned)v);
          need &= ~(1u << pq);
        }
      }
    }
    out[g * BG + tid] = sum;
  }
}

extern "C" void kernel_launch(void* const* d_in, const int* in_sizes, int n_in,
                              void* d_out, int out_size, void* d_ws, size_t ws_size,
                              hipStream_t stream) {
  (void)in_sizes; (void)n_in; (void)out_size; (void)ws_size;
  const float* xd    = (const float*)d_in[0];
  const float* w     = (const float*)d_in[1];
  const float* W_ih  = (const float*)d_in[2];
  const float* b_ih  = (const float*)d_in[3];
  const float* W_hh  = (const float*)d_in[4];
  const float* b_hh  = (const float*)d_in[5];
  const float* W_out = (const float*)d_in[6];
  const float* b_out = (const float*)d_in[7];
  // ws: 2*HBUF + 256 uint64 = ~133 KB. No memset: 0xAA poison tag
  // (0xAAAAAAAA) never equals a valid tag (<= 2049).
  uint64_t* ex = (uint64_t*)d_ws;
  lstm_persist<<<dim3(16), dim3(256), 0, stream>>>(
      xd, w, W_ih, b_ih, W_hh, b_hh, W_out, b_out, (float*)d_out, ex);
}

// Round 4
// 5386.827 us; speedup vs baseline: 1.1557x; 1.1557x over previous
//
#include <hip/hip_runtime.h>
#include <hip/hip_fp16.h>
#include <stdint.h>

// Gated LSTM: B=64, T=2048, I=128, H=256, O=1.
// R4: 32 persistent WGs = 8 batch-groups (g=bid&7 -> partners ALL on one XCD
// under round-robin dispatch; R3 proved cross-XCD polls cost ~1us/step)
// x 4 N-slices (p=bid>>3; 256 z-rows = 64 h-outputs each). M=8 batches/group.
// Weights 192 regs/thread (4 gate-tiles x 12 kt, f16 MFMA B-frags).
// Gate-per-n-tile mapping => all 4 gates of one (m,j) land in one lane's 4
// accumulators => IN-REGISTER epilogue (no Zlds, no 3rd barrier).
// Exchange: tag-embedded {t+1 : 2xf16} relaxed agent atomics, double-buffered
// by t&1; LDS h-region also double-buffered so epilogue's own-h write needs
// no extra barrier. Polls issued at step top, checked after x-part MFMAs.

#define NT 2048
#define NI 128
#define NH 256
#define HBUF 8192   // uint64 words per exchange buffer (32 WG x 256)

typedef _Float16 h8_t __attribute__((ext_vector_type(8)));
typedef _Float16 h4_t __attribute__((ext_vector_type(4)));
typedef _Float16 h2_t __attribute__((ext_vector_type(2)));
typedef float f4_t __attribute__((ext_vector_type(4)));

__device__ __forceinline__ float sigm(float x) {
  return __builtin_amdgcn_rcpf(1.f + __expf(-x));
}
__device__ __forceinline__ float tanh_f(float x) {
  return 1.f - 2.f * __builtin_amdgcn_rcpf(1.f + __expf(2.f * x));
}

// ex (uint64): [buf2][wg32][m8][jp32]  slot = (g*4+p)*256 + m*32 + jp
// final partials at 2*HBUF: (g*4+p)*8 + m, tag 2049.

__launch_bounds__(256, 1)
__global__ void lstm_persist(
    const float* __restrict__ xd, const float* __restrict__ w,
    const float* __restrict__ W_ih, const float* __restrict__ b_ih,
    const float* __restrict__ W_hh, const float* __restrict__ b_hh,
    const float* __restrict__ W_out, const float* __restrict__ b_out,
    float* __restrict__ out, uint64_t* ex)
{
  const int bid = blockIdx.x;
  const int g = bid & 7;        // batch group (same XCD across its 4 slices)
  const int p = bid >> 3;       // N-slice 0..3
  const int tid = threadIdx.x;
  const int lane = tid & 63;
  const int wv = tid >> 6;      // wave 0..3 (owns j = p*64 + wv*16 + cc)
  const int q  = lane >> 4;     // 0..3
  const int cc = lane & 15;

  // A-tile: [m 16][cols: x 0..127 | hbuf0 128..383 | hbuf1 384..639 | pad 8]
  // row stride 648 (=81*16B rows; 324 words % 32 = 4 -> staggered banks)
  __shared__ _Float16 Alds[16][648];
  __shared__ float S[4][8];
  for (int i = tid; i < 16 * 648; i += 256) (&Alds[0][0])[i] = (_Float16)0.f;

  // ---- W B-fragments: n-tile index == gate; n (=cc) == j within wave ----
  // R = gate*256 + p*64 + wv*16 + cc ; k = kt*32 + q*8 (+0..7)
  const int jloc = wv * 16 + cc;
  const int jglob = p * 64 + jloc;
  h8_t wf[4][12];
  for (int gate = 0; gate < 4; ++gate) {
    int R = gate * NH + jglob;
    for (int kt = 0; kt < 12; ++kt) {
      int k = kt * 32 + q * 8;
      const float* s = (k < NI) ? (W_ih + (size_t)R * NI + k)
                                : (W_hh + (size_t)R * NH + (k - NI));
      f4_t lo = *(const f4_t*)s;
      f4_t hi = *(const f4_t*)(s + 4);
      h8_t hh;
      hh[0] = (_Float16)lo[0]; hh[1] = (_Float16)lo[1];
      hh[2] = (_Float16)lo[2]; hh[3] = (_Float16)lo[3];
      hh[4] = (_Float16)hi[0]; hh[5] = (_Float16)hi[1];
      hh[6] = (_Float16)hi[2]; hh[7] = (_Float16)hi[3];
      wf[gate][kt] = hh;
    }
  }
  float bias[4];
  #pragma unroll
  for (int gate = 0; gate < 4; ++gate)
    bias[gate] = b_ih[gate * NH + jglob] + b_hh[gate * NH + jglob];

  // partner slices + poll word coords (thread tid <-> word (m=tid>>5, jp=tid&31))
  int pp[3]; { int c = 0; for (int i = 0; i < 4; ++i) if (i != p) pp[c++] = i; }
  const int wm = tid >> 5, wjp = tid & 31;
  int psl[3];
  #pragma unroll
  for (int s = 0; s < 3; ++s) psl[s] = (g * 4 + pp[s]) * 256 + wm * 32 + wjp;
  const int mybase = (g * 4 + p) * 256;
  const int jp_pub = wv * 8 + (cc >> 1);
  const bool pub = (q < 2) && ((cc & 1) == 0);   // valid m AND even j

  // x prefetch: thread stages 4 floats of row b=tid>>5, col (tid&31)*4
  const int xb = tid >> 5, xc = (tid & 31) * 4;
  const size_t xrow = ((size_t)(g * 8 + xb) * NT) * NI + xc;
  f4_t xa = *(const f4_t*)(xd + xrow);
  f4_t wa = *(const f4_t*)(w + xrow);

  float cst[4] = {0.f, 0.f, 0.f, 0.f};
  float hval[4] = {0.f, 0.f, 0.f, 0.f};

  __syncthreads();   // Alds zeros staged (h^0 = 0, A rows 8..15 = 0 forever)

  for (int t = 0; t < NT; ++t) {
    // ---- issue partner polls (checked after x-part MFMAs) ----
    uint64_t v[3];
    const uint64_t* hb = ex + (size_t)(t & 1) * HBUF;
    if (t > 0) {
      #pragma unroll
      for (int s = 0; s < 3; ++s)
        v[s] = __hip_atomic_load(hb + psl[s], __ATOMIC_RELAXED,
                                 __HIP_MEMORY_SCOPE_AGENT);
    }

    // ---- stage gated x_t from prefetched regs; prefetch t+1 ----
    {
      h4_t gx;
      gx[0] = (_Float16)(xa[0] * sigm(wa[0]));
      gx[1] = (_Float16)(xa[1] * sigm(wa[1]));
      gx[2] = (_Float16)(xa[2] * sigm(wa[2]));
      gx[3] = (_Float16)(xa[3] * sigm(wa[3]));
      *(h4_t*)(&Alds[xb][xc]) = gx;
      size_t xo = xrow + (size_t)((t + 1 < NT) ? t + 1 : NT - 1) * NI;
      xa = *(const f4_t*)(xd + xo);
      wa = *(const f4_t*)(w + xo);
    }
    __syncthreads();                   // barrier A: x staged

    // ---- x-part MFMAs (kt 0..3) while polls fly ----
    f4_t acc[4];
    #pragma unroll
    for (int n = 0; n < 4; ++n) acc[n] = (f4_t){0.f, 0.f, 0.f, 0.f};
    #pragma unroll
    for (int kt = 0; kt < 4; ++kt) {
      h8_t af = *(const h8_t*)(&Alds[cc][kt * 32 + q * 8]);
      #pragma unroll
      for (int gate = 0; gate < 4; ++gate)
        acc[gate] = __builtin_amdgcn_mfma_f32_16x16x32_f16(
            af, wf[gate][kt], acc[gate], 0, 0, 0);
    }

    // ---- check polls, stage partner h^t into hbuf(t&1) ----
    const int hcol = 128 + (t & 1) * 256;
    if (t > 0) {
      unsigned need = 0x7;
      while (need) {
        #pragma unroll
        for (int s = 0; s < 3; ++s) {
          if (!(need & (1u << s))) continue;
          if ((unsigned)(v[s] >> 32) == (unsigned)t) {
            h2_t hp = __builtin_bit_cast(h2_t, (uint32_t)v[s]);
            *(h2_t*)(&Alds[wm][hcol + pp[s] * 64 + 2 * wjp]) = hp;
            need &= ~(1u << s);
          } else {
            v[s] = __hip_atomic_load(hb + psl[s], __ATOMIC_RELAXED,
                                     __HIP_MEMORY_SCOPE_AGENT);
          }
        }
      }
    }
    __syncthreads();                   // barrier B: h staged

    // ---- h-part MFMAs (kt 4..11) ----
    #pragma unroll
    for (int kt = 0; kt < 8; ++kt) {
      h8_t af = *(const h8_t*)(&Alds[cc][hcol + kt * 32 + q * 8]);
      #pragma unroll
      for (int gate = 0; gate < 4; ++gate)
        acc[gate] = __builtin_amdgcn_mfma_f32_16x16x32_f16(
            af, wf[gate][kt + 4], acc[gate], 0, 0, 0);
    }

    // ---- in-register epilogue (lane has all 4 gates of (m=q*4+rr, jglob)) ----
    const int hcol1 = 128 + ((t + 1) & 1) * 256;
    uint64_t* ob = ex + (size_t)((t + 1) & 1) * HBUF + mybase;
    #pragma unroll
    for (int rr = 0; rr < 4; ++rr) {
      float zi = acc[0][rr] + bias[0];
      float zf = acc[1][rr] + bias[1];
      float zg = acc[2][rr] + bias[2];
      float zo = acc[3][rr] + bias[3];
      cst[rr] = sigm(zf) * cst[rr] + sigm(zi) * tanh_f(zg);
      hval[rr] = sigm(zo) * tanh_f(cst[rr]);
      float hn = __shfl_xor(hval[rr], 1, 64);   // neighbor j (cc^1)
      if (pub) {
        h2_t hp; hp[0] = (_Float16)hval[rr]; hp[1] = (_Float16)hn;
        *(h2_t*)(&Alds[q * 4 + rr][hcol1 + p * 64 + 2 * jp_pub]) = hp;
        uint32_t pk = __builtin_bit_cast(uint32_t, hp);
        __hip_atomic_store(ob + (q * 4 + rr) * 32 + jp_pub,
                           (((uint64_t)(unsigned)(t + 1)) << 32) | pk,
                           __ATOMIC_RELAXED, __HIP_MEMORY_SCOPE_AGENT);
      }
    }
    // next step's barrier A orders epilogue LDS writes vs MFMA reads
  }

  // ---- output: out[b] = h_T . W_out + b_out ----
  {
    float wo = W_out[jglob];
    float pv[4];
    #pragma unroll
    for (int rr = 0; rr < 4; ++rr) pv[rr] = (q < 2) ? hval[rr] * wo : 0.f;
    #pragma unroll
    for (int off = 1; off < 16; off <<= 1) {
      #pragma unroll
      for (int rr = 0; rr < 4; ++rr) pv[rr] += __shfl_xor(pv[rr], off, 64);
    }
    if (cc == 0 && q < 2) {
      #pragma unroll
      for (int rr = 0; rr < 4; ++rr) S[wv][q * 4 + rr] = pv[rr];
    }
    __syncthreads();
    if (tid < 8) {
      float s8 = S[0][tid] + S[1][tid] + S[2][tid] + S[3][tid];
      uint64_t* ex2 = ex + 2 * (size_t)HBUF;
      if (p != 0) {
        __hip_atomic_store(ex2 + (g * 4 + p) * 8 + tid,
                           (((uint64_t)2049u) << 32) |
                               (uint64_t)__float_as_uint(s8),
                           __ATOMIC_RELAXED, __HIP_MEMORY_SCOPE_AGENT);
      } else {
        float sum = s8 + b_out[0];
        unsigned need = 0x7;
        while (need) {
          #pragma unroll
          for (int s = 0; s < 3; ++s) {
            if (!(need & (1u << s))) continue;
            uint64_t vv = __hip_atomic_load(ex2 + (g * 4 + pp[s]) * 8 + tid,
                                            __ATOMIC_RELAXED,
                                            __HIP_MEMORY_SCOPE_AGENT);
            if ((unsigned)(vv >> 32) == 2049u) {
              sum += __uint_as_float((unsigned)vv);
              need &= ~(1u << s);
            }
          }
        }
        out[g * 8 + tid] = sum;
      }
    }
  }
}

extern "C" void kernel_launch(void* const* d_in, const int* in_sizes, int n_in,
                              void* d_out, int out_size, void* d_ws, size_t ws_size,
                              hipStream_t stream) {
  (void)in_sizes; (void)n_in; (void)out_size; (void)ws_size;
  const float* xd    = (const float*)d_in[0];
  const float* w     = (const float*)d_in[1];
  const float* W_ih  = (const float*)d_in[2];
  const float* b_ih  = (const float*)d_in[3];
  const float* W_hh  = (const float*)d_in[4];
  const float* b_hh  = (const float*)d_in[5];
  const float* W_out = (const float*)d_in[6];
  const float* b_out = (const float*)d_in[7];
  // ws: (2*HBUF + 256) uint64 = ~133 KB. No memset: 0xAA poison tag
  // (0xAAAAAAAA) never equals a valid tag (<= 2049), and the harness
  // re-poisons ws before every launch so stale tags can't survive either.
  uint64_t* ex = (uint64_t*)d_ws;
  lstm_persist<<<dim3(32), dim3(256), 0, stream>>>(
      xd, w, W_ih, b_ih, W_hh, b_hh, W_out, b_out, (float*)d_out, ex);
}

// Round 5
// 5240.284 us; speedup vs baseline: 1.1881x; 1.0280x over previous
//
#include <hip/hip_runtime.h>
#include <hip/hip_fp16.h>
#include <stdint.h>

// Gated LSTM: B=64, T=2048, I=128, H=256, O=1.
// R5 = R4 shape (32 WGs = 8 same-XCD batch-groups x 4 N-slices, weights
// resident in 192 regs/thread, tag-embedded relaxed-atomic h exchange,
// in-register epilogue) + two critical-path fixes:
//  1) NON-DRAINING BARRIERS: __syncthreads() emits s_waitcnt vmcnt(0) before
//     s_barrier, which drained the t+1 x/w HBM prefetch + publish stores
//     EVERY STEP (~1-2k cyc, the R4 mystery gap). Replace with
//     s_waitcnt lgkmcnt(0) + raw s_barrier: LDS ordering kept, global ops
//     stay in flight. Cross-WG ordering never relied on barriers (tag is
//     inside the 64-bit payload word).
//  2) EPILOGUE LANE-SPREADING: shfl_xor(acc,32) hands rr{2,3} to the idle
//     q>=2 lanes -> all 64 lanes compute 2 (m,j) pairs instead of 32 lanes
//     computing 4 -> halves the serial sigmoid/tanh chain.

#define NT 2048
#define NI 128
#define NH 256
#define HBUF 8192   // uint64 words per exchange buffer (32 WG x 256)

typedef _Float16 h8_t __attribute__((ext_vector_type(8)));
typedef _Float16 h4_t __attribute__((ext_vector_type(4)));
typedef _Float16 h2_t __attribute__((ext_vector_type(2)));
typedef float f4_t __attribute__((ext_vector_type(4)));

__device__ __forceinline__ float sigm(float x) {
  return __builtin_amdgcn_rcpf(1.f + __expf(-x));
}
__device__ __forceinline__ float tanh_f(float x) {
  return 1.f - 2.f * __builtin_amdgcn_rcpf(1.f + __expf(2.f * x));
}

// lgkmcnt(0) only (vmcnt=63, expcnt=7 untouched): imm = 0xC07F
#define BAR() do {                                   \
    __asm__ __volatile__("" ::: "memory");           \
    __builtin_amdgcn_s_waitcnt(0xC07F);              \
    __builtin_amdgcn_s_barrier();                    \
    __asm__ __volatile__("" ::: "memory");           \
  } while (0)

// ex (uint64): [buf2][wg32][m8][jp32]  slot = (g*4+p)*256 + m*32 + jp
// final partials at 2*HBUF: (g*4+p)*8 + m, tag 2049.

__launch_bounds__(256, 1)
__global__ void lstm_persist(
    const float* __restrict__ xd, const float* __restrict__ w,
    const float* __restrict__ W_ih, const float* __restrict__ b_ih,
    const float* __restrict__ W_hh, const float* __restrict__ b_hh,
    const float* __restrict__ W_out, const float* __restrict__ b_out,
    float* __restrict__ out, uint64_t* ex)
{
  const int bid = blockIdx.x;
  const int g = bid & 7;        // batch group (same XCD across its 4 slices)
  const int p = bid >> 3;       // N-slice 0..3
  const int tid = threadIdx.x;
  const int lane = tid & 63;
  const int wv = tid >> 6;      // wave 0..3 (owns j = p*64 + wv*16 + cc)
  const int q  = lane >> 4;     // 0..3
  const int cc = lane & 15;

  // A-tile: [m 16][cols: x 0..127 | hbuf0 128..383 | hbuf1 384..639 | pad 8]
  __shared__ _Float16 Alds[16][648];
  __shared__ float S[4][8];
  for (int i = tid; i < 16 * 648; i += 256) (&Alds[0][0])[i] = (_Float16)0.f;

  // ---- W B-fragments: n-tile index == gate; n (=cc) == j within wave ----
  const int jloc = wv * 16 + cc;
  const int jglob = p * 64 + jloc;
  h8_t wf[4][12];
  for (int gate = 0; gate < 4; ++gate) {
    int R = gate * NH + jglob;
    for (int kt = 0; kt < 12; ++kt) {
      int k = kt * 32 + q * 8;
      const float* s = (k < NI) ? (W_ih + (size_t)R * NI + k)
                                : (W_hh + (size_t)R * NH + (k - NI));
      f4_t lo = *(const f4_t*)s;
      f4_t hi = *(const f4_t*)(s + 4);
      h8_t hh;
      hh[0] = (_Float16)lo[0]; hh[1] = (_Float16)lo[1];
      hh[2] = (_Float16)lo[2]; hh[3] = (_Float16)lo[3];
      hh[4] = (_Float16)hi[0]; hh[5] = (_Float16)hi[1];
      hh[6] = (_Float16)hi[2]; hh[7] = (_Float16)hi[3];
      wf[gate][kt] = hh;
    }
  }
  float bias[4];
  #pragma unroll
  for (int gate = 0; gate < 4; ++gate)
    bias[gate] = b_ih[gate * NH + jglob] + b_hh[gate * NH + jglob];

  // partner slices + poll word coords
  int pp[3]; { int c = 0; for (int i = 0; i < 4; ++i) if (i != p) pp[c++] = i; }
  const int wm = tid >> 5, wjp = tid & 31;
  int psl[3];
  #pragma unroll
  for (int s = 0; s < 3; ++s) psl[s] = (g * 4 + pp[s]) * 256 + wm * 32 + wjp;
  const int mybase = (g * 4 + p) * 256;
  const int jp_pub = wv * 8 + (cc >> 1);
  const bool pub = ((cc & 1) == 0);     // even-j lanes publish (all q now)

  // epilogue pair identity after spreading: e in {0,1}
  //   q<2 : m_e = q*4 + e      (keeps rr 0,1)
  //   q>=2: m_e = (q-2)*4+2+e  (takes rr 2,3 from lane^32)
  const int m0 = (q < 2) ? (q * 4) : ((q - 2) * 4 + 2);
  const int m1 = m0 + 1;

  // x prefetch: thread stages 4 floats of row b=tid>>5, col (tid&31)*4
  const int xb = tid >> 5, xc = (tid & 31) * 4;
  const size_t xrow = ((size_t)(g * 8 + xb) * NT) * NI + xc;
  f4_t xa = *(const f4_t*)(xd + xrow);
  f4_t wa = *(const f4_t*)(w + xrow);

  float cst[2] = {0.f, 0.f};
  float hval[2] = {0.f, 0.f};

  __syncthreads();   // one full barrier at init is fine

  for (int t = 0; t < NT; ++t) {
    // ---- issue partner polls (checked after x-part MFMAs) ----
    uint64_t v[3];
    const uint64_t* hb = ex + (size_t)(t & 1) * HBUF;
    if (t > 0) {
      #pragma unroll
      for (int s = 0; s < 3; ++s)
        v[s] = __hip_atomic_load(hb + psl[s], __ATOMIC_RELAXED,
                                 __HIP_MEMORY_SCOPE_AGENT);
    }

    // ---- stage gated x_t from prefetched regs; prefetch t+1 ----
    {
      h4_t gx;
      gx[0] = (_Float16)(xa[0] * sigm(wa[0]));
      gx[1] = (_Float16)(xa[1] * sigm(wa[1]));
      gx[2] = (_Float16)(xa[2] * sigm(wa[2]));
      gx[3] = (_Float16)(xa[3] * sigm(wa[3]));
      *(h4_t*)(&Alds[xb][xc]) = gx;
      size_t xo = xrow + (size_t)((t + 1 < NT) ? t + 1 : NT - 1) * NI;
      xa = *(const f4_t*)(xd + xo);
      wa = *(const f4_t*)(w + xo);
    }
    BAR();                             // barrier A: x staged (prefetch stays in flight)

    // ---- x-part MFMAs (kt 0..3) while polls fly ----
    f4_t acc[4];
    #pragma unroll
    for (int n = 0; n < 4; ++n) acc[n] = (f4_t){0.f, 0.f, 0.f, 0.f};
    #pragma unroll
    for (int kt = 0; kt < 4; ++kt) {
      h8_t af = *(const h8_t*)(&Alds[cc][kt * 32 + q * 8]);
      #pragma unroll
      for (int gate = 0; gate < 4; ++gate)
        acc[gate] = __builtin_amdgcn_mfma_f32_16x16x32_f16(
            af, wf[gate][kt], acc[gate], 0, 0, 0);
    }

    // ---- check polls, stage partner h^t into hbuf(t&1) ----
    const int hcol = 128 + (t & 1) * 256;
    if (t > 0) {
      unsigned need = 0x7;
      while (need) {
        #pragma unroll
        for (int s = 0; s < 3; ++s) {
          if (!(need & (1u << s))) continue;
          if ((unsigned)(v[s] >> 32) == (unsigned)t) {
            h2_t hp = __builtin_bit_cast(h2_t, (uint32_t)v[s]);
            *(h2_t*)(&Alds[wm][hcol + pp[s] * 64 + 2 * wjp]) = hp;
            need &= ~(1u << s);
          } else {
            v[s] = __hip_atomic_load(hb + psl[s], __ATOMIC_RELAXED,
                                     __HIP_MEMORY_SCOPE_AGENT);
          }
        }
      }
    }
    BAR();                             // barrier B: h staged

    // ---- h-part MFMAs (kt 4..11) ----
    #pragma unroll
    for (int kt = 0; kt < 8; ++kt) {
      h8_t af = *(const h8_t*)(&Alds[cc][hcol + kt * 32 + q * 8]);
      #pragma unroll
      for (int gate = 0; gate < 4; ++gate)
        acc[gate] = __builtin_amdgcn_mfma_f32_16x16x32_f16(
            af, wf[gate][kt + 4], acc[gate], 0, 0, 0);
    }

    // ---- spread epilogue: all 64 lanes, 2 (m,j) pairs each ----
    float zz[2][4];
    #pragma unroll
    for (int gate = 0; gate < 4; ++gate) {
      float a2 = __shfl_xor(acc[gate][2], 32, 64);
      float a3 = __shfl_xor(acc[gate][3], 32, 64);
      zz[0][gate] = (q < 2) ? acc[gate][0] : a2;
      zz[1][gate] = (q < 2) ? acc[gate][1] : a3;
    }
    const int hcol1 = 128 + ((t + 1) & 1) * 256;
    uint64_t* ob = ex + (size_t)((t + 1) & 1) * HBUF + mybase;
    #pragma unroll
    for (int e = 0; e < 2; ++e) {
      float zi = zz[e][0] + bias[0];
      float zf = zz[e][1] + bias[1];
      float zg = zz[e][2] + bias[2];
      float zo = zz[e][3] + bias[3];
      cst[e] = sigm(zf) * cst[e] + sigm(zi) * tanh_f(zg);
      hval[e] = sigm(zo) * tanh_f(cst[e]);
      float hn = __shfl_xor(hval[e], 1, 64);   // neighbor j (cc^1)
      int me = e ? m1 : m0;
      if (pub) {
        h2_t hp; hp[0] = (_Float16)hval[e]; hp[1] = (_Float16)hn;
        *(h2_t*)(&Alds[me][hcol1 + p * 64 + 2 * jp_pub]) = hp;
        uint32_t pk = __builtin_bit_cast(uint32_t, hp);
        __hip_atomic_store(ob + me * 32 + jp_pub,
                           (((uint64_t)(unsigned)(t + 1)) << 32) | pk,
                           __ATOMIC_RELAXED, __HIP_MEMORY_SCOPE_AGENT);
      }
    }
    // next step's barrier A orders epilogue LDS writes vs MFMA reads
  }

  // ---- output: out[b] = h_T . W_out + b_out ----
  {
    float wo = W_out[jglob];
    float pv0 = hval[0] * wo, pv1 = hval[1] * wo;
    #pragma unroll
    for (int off = 1; off < 16; off <<= 1) {   // reduce over cc (same q,wv)
      pv0 += __shfl_xor(pv0, off, 64);
      pv1 += __shfl_xor(pv1, off, 64);
    }
    if (cc == 0) { S[wv][m0] = pv0; S[wv][m1] = pv1; }
    BAR();
    if (tid < 8) {
      float s8 = S[0][tid] + S[1][tid] + S[2][tid] + S[3][tid];
      uint64_t* ex2 = ex + 2 * (size_t)HBUF;
      if (p != 0) {
        __hip_atomic_store(ex2 + (g * 4 + p) * 8 + tid,
                           (((uint64_t)2049u) << 32) |
                               (uint64_t)__float_as_uint(s8),
                           __ATOMIC_RELAXED, __HIP_MEMORY_SCOPE_AGENT);
      } else {
        float sum = s8 + b_out[0];
        unsigned need = 0x7;
        while (need) {
          #pragma unroll
          for (int s = 0; s < 3; ++s) {
            if (!(need & (1u << s))) continue;
            uint64_t vv = __hip_atomic_load(ex2 + (g * 4 + pp[s]) * 8 + tid,
                                            __ATOMIC_RELAXED,
                                            __HIP_MEMORY_SCOPE_AGENT);
            if ((unsigned)(vv >> 32) == 2049u) {
              sum += __uint_as_float((unsigned)vv);
              need &= ~(1u << s);
            }
          }
        }
        out[g * 8 + tid] = sum;
      }
    }
  }
}

extern "C" void kernel_launch(void* const* d_in, const int* in_sizes, int n_in,
                              void* d_out, int out_size, void* d_ws, size_t ws_size,
                              hipStream_t stream) {
  (void)in_sizes; (void)n_in; (void)out_size; (void)ws_size;
  const float* xd    = (const float*)d_in[0];
  const float* w     = (const float*)d_in[1];
  const float* W_ih  = (const float*)d_in[2];
  const float* b_ih  = (const float*)d_in[3];
  const float* W_hh  = (const float*)d_in[4];
  const float* b_hh  = (const float*)d_in[5];
  const float* W_out = (const float*)d_in[6];
  const float* b_out = (const float*)d_in[7];
  // ws: (2*HBUF + 256) uint64 = ~133 KB. No memset: 0xAA poison tag
  // (0xAAAAAAAA) never equals a valid tag (<= 2049).
  uint64_t* ex = (uint64_t*)d_ws;
  lstm_persist<<<dim3(32), dim3(256), 0, stream>>>(
      xd, w, W_ih, b_ih, W_hh, b_hh, W_out, b_out, (float*)d_out, ex);
}